// Round 8
// baseline (468.837 us; speedup 1.0000x reference)
//
#include <hip/hip_runtime.h>

constexpr int NN  = 50000;   // nodes
constexpr int NE  = 800000;  // edges
constexpr int CIN = 128;     // input channels
constexpr int CH  = 256;     // hidden channels
constexpr int NG  = 512;     // graphs

typedef unsigned short ushort_t;
typedef unsigned int uint_t;

static __device__ __forceinline__ ushort_t f2bf(float f) {
    uint_t u = __float_as_uint(f);
    u += 0x7fffu + ((u >> 16) & 1u);   // round-to-nearest-even
    return (ushort_t)(u >> 16);
}

// ================= prep: fp32 -> bf16 converts =================
__global__ void conv_x_kernel(const float4* __restrict__ x, ushort4* __restrict__ xb, int n4) {
    int i = blockIdx.x * blockDim.x + threadIdx.x;
    if (i >= n4) return;
    float4 v = x[i];
    ushort4 o;
    o.x = f2bf(v.x); o.y = f2bf(v.y); o.z = f2bf(v.z); o.w = f2bf(v.w);
    xb[i] = o;
}

// all three weights, transposed+converted, in one launch.
// layout i: [0, 32768) -> W0t ; [32768, 98304) -> W1t ; [98304, 163840) -> W2t
__global__ void conv_w_all_kernel(const float* __restrict__ W0, const float* __restrict__ W1,
                                  const float* __restrict__ W2, ushort_t* __restrict__ W0t,
                                  ushort_t* __restrict__ W1t, ushort_t* __restrict__ W2t) {
    int i = blockIdx.x * blockDim.x + threadIdx.x;
    if (i < CIN * CH) {
        int k = i / CH, n = i % CH;
        W0t[(size_t)n * CIN + k] = f2bf(W0[i]);
    } else if (i < CIN * CH + CH * CH) {
        int j = i - CIN * CH;
        int k = j / CH, n = j % CH;
        W1t[(size_t)n * CH + k] = f2bf(W1[j]);
    } else if (i < CIN * CH + 2 * CH * CH) {
        int j = i - CIN * CH - CH * CH;
        int k = j / CH, n = j % CH;
        W2t[(size_t)n * CH + k] = f2bf(W2[j]);
    }
}

// ================= CSR build =================
__global__ void count_kernel(const int* __restrict__ dst, int* __restrict__ cnt, int E) {
    int e = blockIdx.x * blockDim.x + threadIdx.x;
    if (e < E) atomicAdd(&cnt[dst[e]], 1);
}

__global__ __launch_bounds__(256) void scan_bsum_kernel(const int* __restrict__ cnt,
                                                        int* __restrict__ bsum, int n) {
    int i = blockIdx.x * 256 + threadIdx.x;
    int v = (i < n) ? cnt[i] : 0;
    #pragma unroll
    for (int off = 32; off >= 1; off >>= 1) v += __shfl_xor(v, off, 64);
    __shared__ int ws[4];
    if ((threadIdx.x & 63) == 0) ws[threadIdx.x >> 6] = v;
    __syncthreads();
    if (threadIdx.x == 0) bsum[blockIdx.x] = ws[0] + ws[1] + ws[2] + ws[3];
}

__global__ __launch_bounds__(256) void scan_boff_kernel(int* __restrict__ bsum, int nb) {
    int tid = threadIdx.x, lane = tid & 63, wid = tid >> 6;
    int v = (tid < nb) ? bsum[tid] : 0;
    int s = v;
    #pragma unroll
    for (int off = 1; off < 64; off <<= 1) {
        int t = __shfl_up(s, off, 64);
        if (lane >= off) s += t;
    }
    __shared__ int wsum[4];
    if (lane == 63) wsum[wid] = s;
    __syncthreads();
    int wadd = 0;
    #pragma unroll
    for (int w = 0; w < 4; w++) if (w < wid) wadd += wsum[w];
    if (tid < nb) bsum[tid] = wadd + s - v;   // exclusive
}

__global__ __launch_bounds__(256) void scan_final_kernel(const int* __restrict__ cnt,
                                                         const int* __restrict__ boff,
                                                         int* __restrict__ rowptr,
                                                         float* __restrict__ dinv, int n) {
    int tid = threadIdx.x, lane = tid & 63, wid = tid >> 6;
    int i = blockIdx.x * 256 + tid;
    int v = (i < n) ? cnt[i] : 0;
    int s = v;
    #pragma unroll
    for (int off = 1; off < 64; off <<= 1) {
        int t = __shfl_up(s, off, 64);
        if (lane >= off) s += t;
    }
    __shared__ int wsum[4];
    if (lane == 63) wsum[wid] = s;
    __syncthreads();
    int wadd = boff[blockIdx.x];
    #pragma unroll
    for (int w = 0; w < 4; w++) if (w < wid) wadd += wsum[w];
    if (i < n) {
        rowptr[i] = wadd + s - v;
        dinv[i]   = rsqrtf((float)v + 1.0f);   // +1 self loop
        if (i == n - 1) rowptr[n] = wadd + s;
    }
}

// scatter: write packed {src, dinv[src]} per CSR slot
__global__ void scatter_kernel(const int* __restrict__ src, const int* __restrict__ dst,
                               const int* __restrict__ rowptr, int* __restrict__ cursor,
                               const float* __restrict__ dinv, int2* __restrict__ epack, int E) {
    int e = blockIdx.x * blockDim.x + threadIdx.x;
    if (e >= E) return;
    int d = dst[e];
    int s = src[e];
    int p = rowptr[d] + atomicAdd(&cursor[d], 1);
    epack[p] = make_int2(s, __float_as_int(dinv[s]));
}

// ================= per-node gather aggregation (bf16) ====
// One wave per node. 4 B/lane converged loads only; 16-row unroll ->
// 32 outstanding loads/wave for C=256, 16 for C=128 (MLP x latency model).
// MODE 0: out(bf16) = dd*sum + dd^2*self
// MODE 1: out(bf16) = relu(dd*sum + dd^2*self + bias)
// MODE 2: atomicAdd relu(...) into fp32 out[batch[d]]
template <int C, int MODE>
__global__ __launch_bounds__(256) void node_agg_kernel(
    const ushort_t* __restrict__ h, const int* __restrict__ rowptr,
    const int2* __restrict__ epack, const float* __restrict__ dinv,
    const float* __restrict__ bias, const int* __restrict__ batch,
    void* __restrict__ out_v, int n) {
    constexpr int V = C / 64;                 // bf16 per lane (2 or 4)
    constexpr int UF = 16;
    int wave = threadIdx.x >> 6;
    int lane = threadIdx.x & 63;
    int d = blockIdx.x * 4 + wave;
    if (d >= n) return;

    int beg = rowptr[d], end = rowptr[d + 1];
    float acc[V] = {};

    for (int e = beg; e < end; e += UF) {
        int   srcs[UF];
        float wts[UF];
        #pragma unroll
        for (int u = 0; u < UF; u++) {
            int idx = e + u;
            int2 ep = epack[min(idx, NE - 1)];
            bool a = idx < end;               // wave-uniform
            srcs[u] = a ? ep.x : d;           // fallback: self row (L1-hot)
            wts[u]  = a ? __int_as_float(ep.y) : 0.0f;
        }
        if constexpr (V == 4) {
            uint_t ra[UF], rb[UF];
            #pragma unroll
            for (int u = 0; u < UF; u++) {
                const uint_t* row = (const uint_t*)(h + (size_t)srcs[u] * C);
                ra[u] = row[lane];            // channels 2l,2l+1
                rb[u] = row[64 + lane];       // channels 128+2l,128+2l+1
            }
            #pragma unroll
            for (int u = 0; u < UF; u++) {
                float w = wts[u];
                acc[0] += w * __uint_as_float(ra[u] << 16);
                acc[1] += w * __uint_as_float(ra[u] & 0xffff0000u);
                acc[2] += w * __uint_as_float(rb[u] << 16);
                acc[3] += w * __uint_as_float(rb[u] & 0xffff0000u);
            }
        } else {
            uint_t rv[UF];
            #pragma unroll
            for (int u = 0; u < UF; u++)
                rv[u] = ((const uint_t*)(h + (size_t)srcs[u] * C))[lane];
            #pragma unroll
            for (int u = 0; u < UF; u++) {
                float w = wts[u];
                acc[0] += w * __uint_as_float(rv[u] << 16);
                acc[1] += w * __uint_as_float(rv[u] & 0xffff0000u);
            }
        }
    }

    float dd = dinv[d];
    float self[V];
    {
        const uint_t* row = (const uint_t*)(h + (size_t)d * C);
        uint_t sa = row[lane];
        self[0] = __uint_as_float(sa << 16);
        self[1] = __uint_as_float(sa & 0xffff0000u);
        if constexpr (V == 4) {
            uint_t sb = row[64 + lane];
            self[2] = __uint_as_float(sb << 16);
            self[3] = __uint_as_float(sb & 0xffff0000u);
        }
    }

    float r[V];
    if constexpr (MODE >= 1) {
        float2 bA = *(const float2*)(bias + 2 * lane);
        r[0] = fmaxf(dd * acc[0] + dd * dd * self[0] + bA.x, 0.0f);
        r[1] = fmaxf(dd * acc[1] + dd * dd * self[1] + bA.y, 0.0f);
        if constexpr (V == 4) {
            float2 bB = *(const float2*)(bias + 128 + 2 * lane);
            r[2] = fmaxf(dd * acc[2] + dd * dd * self[2] + bB.x, 0.0f);
            r[3] = fmaxf(dd * acc[3] + dd * dd * self[3] + bB.y, 0.0f);
        }
    } else {
        #pragma unroll
        for (int i = 0; i < V; i++)
            r[i] = dd * acc[i] + dd * dd * self[i];
    }

    if constexpr (MODE == 2) {
        float* o = (float*)out_v + (size_t)batch[d] * C;
        atomicAdd(o + 2 * lane, r[0]);
        atomicAdd(o + 2 * lane + 1, r[1]);
        if constexpr (V == 4) {
            atomicAdd(o + 128 + 2 * lane, r[2]);
            atomicAdd(o + 128 + 2 * lane + 1, r[3]);
        }
    } else {
        uint_t* o = (uint_t*)((ushort_t*)out_v + (size_t)d * C);
        o[lane] = (uint_t)f2bf(r[0]) | ((uint_t)f2bf(r[1]) << 16);
        if constexpr (V == 4)
            o[64 + lane] = (uint_t)f2bf(r[2]) | ((uint_t)f2bf(r[3]) << 16);
    }
}

// ================= bf16 MFMA GEMM: C[M,256] = A[M,K] @ Wt[N,K]^T =================
// Software-pipelined: next K-tile prefetched into registers during MFMA.
typedef __attribute__((ext_vector_type(8))) short bf16x8;
typedef __attribute__((ext_vector_type(4))) float f32x4;

template <int MODE>
__global__ __launch_bounds__(256) void gemm_bf16_kernel(
    const ushort_t* __restrict__ A, const ushort_t* __restrict__ Wt,
    const float* __restrict__ bias, ushort_t* __restrict__ C, int M, int K) {
    __shared__ ushort_t As[128][40];
    __shared__ ushort_t Bs[128][40];
    int tid = threadIdx.x;
    int row0 = blockIdx.x * 128, col0 = blockIdx.y * 128;
    int lr = tid >> 2, lq = tid & 3;
    int lane = tid & 63, wv = tid >> 6;
    int wr = (wv >> 1) * 64, wc = (wv & 1) * 64;
    int r16 = lane & 15, quad = lane >> 4;

    int gr0 = row0 + lr, gr1 = row0 + lr + 64;
    const ushort_t* pa0 = A + (size_t)gr0 * K + lq * 8;
    const ushort_t* pa1 = A + (size_t)gr1 * K + lq * 8;
    const ushort_t* pb0 = Wt + (size_t)(col0 + lr) * K + lq * 8;
    const ushort_t* pb1 = Wt + (size_t)(col0 + lr + 64) * K + lq * 8;
    bool va0 = gr0 < M, va1 = gr1 < M;

    f32x4 acc[4][4] = {};

    uint4 a0 = make_uint4(0, 0, 0, 0), a1 = make_uint4(0, 0, 0, 0);
    if (va0) a0 = *(const uint4*)pa0;
    if (va1) a1 = *(const uint4*)pa1;
    uint4 b0 = *(const uint4*)pb0;
    uint4 b1 = *(const uint4*)pb1;

    for (int k0 = 0; k0 < K; k0 += 32) {
        *(uint4*)&As[lr][lq * 8]      = a0;
        *(uint4*)&As[lr + 64][lq * 8] = a1;
        *(uint4*)&Bs[lr][lq * 8]      = b0;
        *(uint4*)&Bs[lr + 64][lq * 8] = b1;
        __syncthreads();

        int kn = k0 + 32;
        if (kn < K) {   // prefetch next tile during MFMA
            a0 = va0 ? *(const uint4*)(pa0 + kn) : make_uint4(0, 0, 0, 0);
            a1 = va1 ? *(const uint4*)(pa1 + kn) : make_uint4(0, 0, 0, 0);
            b0 = *(const uint4*)(pb0 + kn);
            b1 = *(const uint4*)(pb1 + kn);
        }

        bf16x8 af[4], bfr[4];
        #pragma unroll
        for (int i = 0; i < 4; i++) af[i]  = *(const bf16x8*)&As[wr + i * 16 + r16][quad * 8];
        #pragma unroll
        for (int j = 0; j < 4; j++) bfr[j] = *(const bf16x8*)&Bs[wc + j * 16 + r16][quad * 8];
        #pragma unroll
        for (int i = 0; i < 4; i++)
            #pragma unroll
            for (int j = 0; j < 4; j++)
                acc[i][j] = __builtin_amdgcn_mfma_f32_16x16x32_bf16(af[i], bfr[j], acc[i][j], 0, 0, 0);
        __syncthreads();
    }

    #pragma unroll
    for (int j = 0; j < 4; j++) {
        int colc = col0 + wc + j * 16 + r16;
        float bval = (MODE == 1) ? bias[colc] : 0.0f;
        #pragma unroll
        for (int i = 0; i < 4; i++) {
            #pragma unroll
            for (int r = 0; r < 4; r++) {
                int row = row0 + wr + i * 16 + quad * 4 + r;
                if (row < M) {
                    float v = acc[i][j][r];
                    if (MODE == 1) v = fmaxf(v + bval, 0.0f);
                    C[(size_t)row * 256 + colc] = f2bf(v);
                }
            }
        }
    }
}

extern "C" void kernel_launch(void* const* d_in, const int* in_sizes, int n_in,
                              void* d_out, int out_size, void* d_ws, size_t ws_size,
                              hipStream_t stream) {
    const float* x   = (const float*)d_in[0];
    const float* W0  = (const float*)d_in[1];
    const float* b0  = (const float*)d_in[2];
    const float* W1  = (const float*)d_in[3];
    const float* b1  = (const float*)d_in[4];
    const float* W2  = (const float*)d_in[5];
    const float* b2  = (const float*)d_in[6];
    const int*   ei  = (const int*)d_in[7];
    const int*   src = ei;
    const int*   dst = ei + NE;
    const int*   batch = (const int*)d_in[8];
    float* out = (float*)d_out;

    char* ws = (char*)d_ws;
    ushort_t* Abf = (ushort_t*)ws;                        // [NN,256] bf16  25.6 MB
    ushort_t* Bbf = (ushort_t*)(ws + 25600000ull);        // [NN,256] bf16  25.6 MB
    ushort_t* xbf = (ushort_t*)(ws + 51200000ull);        // [NN,128] bf16  12.8 MB
    ushort_t* W0t = (ushort_t*)(ws + 64000000ull);        // [256,128] bf16
    ushort_t* W1t = (ushort_t*)(ws + 64065536ull);        // [256,256] bf16
    ushort_t* W2t = (ushort_t*)(ws + 64196608ull);        // [256,256] bf16
    float*    dinv   = (float*)(ws + 64327680ull);        // [NN]
    int*      rowptr = (int*)  (ws + 64527680ull);        // [NN+1]
    int*      cnt    = (int*)  (ws + 64727808ull);        // [NN]
    int2*     epack  = (int2*) (ws + 64927808ull);        // [NE] {src, dinv[src]} 6.4 MB
    int*      bsum   = (int*)  (ws + 71327808ull);        // [<=256]

    const int scanBlocks = (NN + 255) / 256;              // 196
    const int nodeBlocks = (NN + 3) / 4;                  // 1 node per wave, 4 waves/block
    const dim3 ggrid((NN + 127) / 128, 2);
    const int wElems = CIN * CH + 2 * CH * CH;            // 163840

    // --- prep converts ---
    conv_x_kernel<<<(NN * CIN / 4 + 255) / 256, 256, 0, stream>>>((const float4*)x, (ushort4*)xbf, NN * CIN / 4);
    conv_w_all_kernel<<<(wElems + 255) / 256, 256, 0, stream>>>(W0, W1, W2, W0t, W1t, W2t);

    // --- CSR + normalization ---
    hipMemsetAsync(cnt, 0, (size_t)NN * 4, stream);
    count_kernel<<<(NE + 255) / 256, 256, 0, stream>>>(dst, cnt, NE);
    scan_bsum_kernel<<<scanBlocks, 256, 0, stream>>>(cnt, bsum, NN);
    scan_boff_kernel<<<1, 256, 0, stream>>>(bsum, scanBlocks);
    scan_final_kernel<<<scanBlocks, 256, 0, stream>>>(cnt, bsum, rowptr, dinv, NN);
    hipMemsetAsync(cnt, 0, (size_t)NN * 4, stream);       // reuse as cursor
    scatter_kernel<<<(NE + 255) / 256, 256, 0, stream>>>(src, dst, rowptr, cnt, dinv, epack, NE);

    // --- layer 0: aggregate x (128 ch), GEMM0 fused bias+relu ---
    node_agg_kernel<CIN, 0><<<nodeBlocks, 256, 0, stream>>>(xbf, rowptr, epack, dinv, nullptr, nullptr, Bbf, NN);
    gemm_bf16_kernel<1><<<ggrid, 256, 0, stream>>>(Bbf, W0t, b0, Abf, NN, CIN);

    // --- layer 1: GEMM1 plain, aggregate fused bias+relu ---
    gemm_bf16_kernel<0><<<ggrid, 256, 0, stream>>>(Abf, W1t, nullptr, Bbf, NN, CH);
    node_agg_kernel<CH, 1><<<nodeBlocks, 256, 0, stream>>>(Bbf, rowptr, epack, dinv, b1, nullptr, Abf, NN);

    // --- layer 2: GEMM2 plain, aggregate fused bias+relu+pool ---
    gemm_bf16_kernel<0><<<ggrid, 256, 0, stream>>>(Abf, W2t, nullptr, Bbf, NN, CH);
    hipMemsetAsync(out, 0, (size_t)NG * CH * 4, stream);
    node_agg_kernel<CH, 2><<<nodeBlocks, 256, 0, stream>>>(Bbf, rowptr, epack, dinv, b2, batch, out, NN);
}